// Round 4
// baseline (252.421 us; speedup 1.0000x reference)
//
#include <hip/hip_runtime.h>
#include <hip/hip_bf16.h>

// ---------------------------------------------------------------------------
// Compile-time computation of the real Wigner-3j tables, mirroring the Python
// reference (_cg, _w3j_complex, _Q, _real_w3j) in double precision.
// PATH_W = sqrt(2*lo+1) is folded into the tables.
// ---------------------------------------------------------------------------

struct Tbl { double v[5][5][5]; };   // max (2l+1)=5 per axis; zero padded
struct CMat { double re[5][5]; double im[5][5]; };

constexpr double cfact(int n) {
    double r = 1.0;
    for (int i = 2; i <= n; ++i) r *= (double)i;
    return r;
}

constexpr double csqrt(double x) {
    if (x <= 0.0) return 0.0;
    double g = x > 1.0 ? x : 1.0;
    for (int i = 0; i < 100; ++i) g = 0.5 * (g + x / g);
    return g;
}

constexpr int cparity(int k) { return (((k % 2) + 2) % 2 == 0) ? 1 : -1; }

constexpr double ccg(int l1, int l2, int l3, int m1, int m2, int m3) {
    if (m1 + m2 != m3) return 0.0;
    double pre = csqrt((2.0 * l3 + 1.0) * cfact(l3 + l1 - l2) * cfact(l3 - l1 + l2) *
                       cfact(l1 + l2 - l3) / cfact(l1 + l2 + l3 + 1));
    pre *= csqrt(cfact(l3 + m3) * cfact(l3 - m3) * cfact(l1 - m1) * cfact(l1 + m1) *
                 cfact(l2 - m2) * cfact(l2 + m2));
    int kmin = 0;
    if (l2 - l3 - m1 > kmin) kmin = l2 - l3 - m1;
    if (l1 - l3 + m2 > kmin) kmin = l1 - l3 + m2;
    int kmax = l1 + l2 - l3;
    if (l1 - m1 < kmax) kmax = l1 - m1;
    if (l2 + m2 < kmax) kmax = l2 + m2;
    double s = 0.0;
    for (int k = kmin; k <= kmax; ++k) {
        s += (double)cparity(k) /
             (cfact(k) * cfact(l1 + l2 - l3 - k) * cfact(l1 - m1 - k) * cfact(l2 + m2 - k) *
              cfact(l3 - l2 + m1 + k) * cfact(l3 - l1 - m2 + k));
    }
    return pre * s;
}

constexpr Tbl cw3j_complex(int l1, int l2, int l3) {
    Tbl w{};
    for (int m1 = -l1; m1 <= l1; ++m1)
        for (int m2 = -l2; m2 <= l2; ++m2) {
            int m3 = -(m1 + m2);
            if (m3 >= -l3 && m3 <= l3) {
                w.v[m1 + l1][m2 + l2][m3 + l3] =
                    (double)cparity(l1 - l2 - m3) * ccg(l1, l2, l3, m1, m2, m1 + m2) /
                    csqrt(2.0 * l3 + 1.0);
            }
        }
    return w;
}

constexpr CMat cQ(int l) {
    CMat q{};
    q.re[l][l] = 1.0;
    double s2 = csqrt(2.0);
    for (int m = 1; m <= l; ++m) {
        q.re[l + m][l + m] = (double)cparity(m) / s2;
        q.re[l + m][l - m] = 1.0 / s2;
        q.im[l - m][l - m] = 1.0 / s2;
        q.im[l - m][l + m] = -(double)cparity(m) / s2;
    }
    return q;
}

constexpr Tbl creal_w3j(int l1, int l2, int l3) {
    const CMat q1 = cQ(l1), q2 = cQ(l2), q3 = cQ(l3);
    const Tbl w = cw3j_complex(l1, l2, l3);
    const int n1 = 2 * l1 + 1, n2 = 2 * l2 + 1, n3 = 2 * l3 + 1;
    Tbl t1re{}, t1im{};
    for (int A = 0; A < n1; ++A)
        for (int B = 0; B < n2; ++B)
            for (int c = 0; c < n3; ++c) {
                double re = 0.0, im = 0.0;
                for (int C = 0; C < n3; ++C) {
                    re += w.v[A][B][C] * q3.re[c][C];
                    im += w.v[A][B][C] * q3.im[c][C];
                }
                t1re.v[A][B][c] = re;
                t1im.v[A][B][c] = im;
            }
    Tbl t2re{}, t2im{};
    for (int A = 0; A < n1; ++A)
        for (int b = 0; b < n2; ++b)
            for (int c = 0; c < n3; ++c) {
                double re = 0.0, im = 0.0;
                for (int B = 0; B < n2; ++B) {
                    re += q2.re[b][B] * t1re.v[A][B][c] - q2.im[b][B] * t1im.v[A][B][c];
                    im += q2.re[b][B] * t1im.v[A][B][c] + q2.im[b][B] * t1re.v[A][B][c];
                }
                t2re.v[A][b][c] = re;
                t2im.v[A][b][c] = im;
            }
    Tbl Tre{}, Tim{};
    for (int a = 0; a < n1; ++a)
        for (int b = 0; b < n2; ++b)
            for (int c = 0; c < n3; ++c) {
                double re = 0.0, im = 0.0;
                for (int A = 0; A < n1; ++A) {
                    re += q1.re[a][A] * t2re.v[A][b][c] - q1.im[a][A] * t2im.v[A][b][c];
                    im += q1.re[a][A] * t2im.v[A][b][c] + q1.im[a][A] * t2re.v[A][b][c];
                }
                Tre.v[a][b][c] = re;
                Tim.v[a][b][c] = im;
            }
    double nre = 0.0, nim = 0.0;
    for (int a = 0; a < n1; ++a)
        for (int b = 0; b < n2; ++b)
            for (int c = 0; c < n3; ++c) {
                nre += Tre.v[a][b][c] * Tre.v[a][b][c];
                nim += Tim.v[a][b][c] * Tim.v[a][b][c];
            }
    const bool useRe = (nre >= nim);
    const double norm = csqrt(useRe ? nre : nim);
    Tbl out{};
    for (int a = 0; a < n1; ++a)
        for (int b = 0; b < n2; ++b)
            for (int c = 0; c < n3; ++c) {
                float t32 = (float)((useRe ? Tre.v[a][b][c] : Tim.v[a][b][c]) / norm);
                out.v[a][b][c] = (double)t32 * csqrt(2.0 * l3 + 1.0);
            }
    return out;
}

constexpr Tbl CG[15] = {
    creal_w3j(0, 0, 0), creal_w3j(0, 1, 1), creal_w3j(0, 2, 2), creal_w3j(1, 0, 1),
    creal_w3j(1, 1, 0), creal_w3j(1, 1, 1), creal_w3j(1, 1, 2), creal_w3j(1, 2, 1),
    creal_w3j(1, 2, 2), creal_w3j(2, 0, 2), creal_w3j(2, 1, 1), creal_w3j(2, 1, 2),
    creal_w3j(2, 2, 0), creal_w3j(2, 2, 1), creal_w3j(2, 2, 2)};

// ---------------------------------------------------------------------------
// Kernel: single-wave persistent blocks, 2-stage software pipeline.
//   compute(g) -> LDS bufX ; prefetch loads(g+1) ; stream bufX -> global
// Single wave => no s_barrier needed, but the cross-lane LDS handoff (write
// scattered, read transposed) needs a COMPILER ordering fence + lgkmcnt(0).
// Crucially this does NOT drain vmcnt: prefetch loads and streaming stores
// stay in flight across iterations.
// ---------------------------------------------------------------------------

#define DIM1_C 576
#define DIM2_C 9
#define WDIM_C 960
#define ODIM_C 3264

__device__ __forceinline__ void lds_fence() {
    __builtin_amdgcn_sched_barrier(0);
    asm volatile("s_waitcnt lgkmcnt(0)" ::: "memory");
    __builtin_amdgcn_sched_barrier(0);
}

struct Frag {
    float a0[1], a1[3], a2[5];
    float b0[1], b1[3], b2[5];
    float w[15];
};

__device__ __forceinline__ void load_frag(const float* __restrict__ x1,
                                          const float* __restrict__ x2,
                                          const float* __restrict__ wgt, int e, int u, Frag& f) {
    const float* __restrict__ x1e = x1 + (size_t)e * DIM1_C;
    const float* __restrict__ x2e = x2 + (size_t)e * DIM2_C;
    const float* __restrict__ we = wgt + (size_t)e * WDIM_C;
    f.a0[0] = x1e[u];
#pragma unroll
    for (int i = 0; i < 3; ++i) f.a1[i] = x1e[64 + u * 3 + i];
#pragma unroll
    for (int i = 0; i < 5; ++i) f.a2[i] = x1e[256 + u * 5 + i];
    f.b0[0] = x2e[0];
#pragma unroll
    for (int j = 0; j < 3; ++j) f.b1[j] = x2e[1 + j];
#pragma unroll
    for (int j = 0; j < 5; ++j) f.b2[j] = x2e[4 + j];
#pragma unroll
    for (int p = 0; p < 15; ++p) f.w[p] = we[p * 64 + u];
}

template <int IDX, int N1, int N2, int N3>
__device__ __forceinline__ void do_path(const float (&a)[N1], const float (&b)[N2], float w,
                                        float* op) {
    float t[N3];
#pragma unroll
    for (int k = 0; k < N3; ++k) t[k] = 0.0f;
#pragma unroll
    for (int i = 0; i < N1; ++i) {
#pragma unroll
        for (int j = 0; j < N2; ++j) {
            const float p = a[i] * b[j];
#pragma unroll
            for (int k = 0; k < N3; ++k) {
                constexpr const Tbl& T = CG[IDX];
                const float c = (float)T.v[i][j][k];
                if (c != 0.0f) t[k] = fmaf(c, p, t[k]);
            }
        }
    }
#pragma unroll
    for (int k = 0; k < N3; ++k) op[k] = t[k] * w;
}

__device__ __forceinline__ void compute_to_lds(const Frag& f, float* buf, int u) {
    do_path<0, 1, 1, 1>(f.a0, f.b0, f.w[0], buf + 0 + u * 1);
    do_path<1, 1, 3, 3>(f.a0, f.b1, f.w[1], buf + 64 + u * 3);
    do_path<2, 1, 5, 5>(f.a0, f.b2, f.w[2], buf + 256 + u * 5);
    do_path<3, 3, 1, 3>(f.a1, f.b0, f.w[3], buf + 576 + u * 3);
    do_path<4, 3, 3, 1>(f.a1, f.b1, f.w[4], buf + 768 + u * 1);
    do_path<5, 3, 3, 3>(f.a1, f.b1, f.w[5], buf + 832 + u * 3);
    do_path<6, 3, 3, 5>(f.a1, f.b1, f.w[6], buf + 1024 + u * 5);
    do_path<7, 3, 5, 3>(f.a1, f.b2, f.w[7], buf + 1344 + u * 3);
    do_path<8, 3, 5, 5>(f.a1, f.b2, f.w[8], buf + 1536 + u * 5);
    do_path<9, 5, 1, 5>(f.a2, f.b0, f.w[9], buf + 1856 + u * 5);
    do_path<10, 5, 3, 3>(f.a2, f.b1, f.w[10], buf + 2176 + u * 3);
    do_path<11, 5, 3, 5>(f.a2, f.b1, f.w[11], buf + 2368 + u * 5);
    do_path<12, 5, 5, 1>(f.a2, f.b2, f.w[12], buf + 2688 + u * 1);
    do_path<13, 5, 5, 3>(f.a2, f.b2, f.w[13], buf + 2752 + u * 3);
    do_path<14, 5, 5, 5>(f.a2, f.b2, f.w[14], buf + 2944 + u * 5);
}

__device__ __forceinline__ void stream_out(const float* buf, float* __restrict__ out, int e,
                                           int u) {
    float4* __restrict__ outv = (float4*)(out + (size_t)e * ODIM_C);
    const float4* sv = (const float4*)buf;
#pragma unroll
    for (int it = 0; it < 12; ++it) outv[u + it * 64] = sv[u + it * 64];
    if (u < 48) outv[u + 768] = sv[u + 768];  // 816 = 12*64 + 48
}

__global__ __launch_bounds__(64) void tp_kernel(const float* __restrict__ x1,
                                                const float* __restrict__ x2,
                                                const float* __restrict__ wgt,
                                                float* __restrict__ out, int n) {
    __shared__ __align__(16) float bufA[ODIM_C];
    __shared__ __align__(16) float bufB[ODIM_C];
    const int u = threadIdx.x & 63;
    const int stride = gridDim.x;
    int e = (int)blockIdx.x;
    if (e >= n) return;

    Frag f, g;
    load_frag(x1, x2, wgt, e, u, f);

    while (true) {
        // ---- stage A ----
        compute_to_lds(f, bufA, u);
        int en = e + stride;
        bool more = en < n;
        if (more) load_frag(x1, x2, wgt, en, u, g);  // prefetch BEFORE stores
        lds_fence();                                 // order ds_write -> ds_read (cross-lane)
        stream_out(bufA, out, e, u);
        if (!more) return;
        e = en;

        // ---- stage B ----
        compute_to_lds(g, bufB, u);
        en = e + stride;
        more = en < n;
        if (more) load_frag(x1, x2, wgt, en, u, f);  // prefetch BEFORE stores
        lds_fence();
        stream_out(bufB, out, e, u);
        if (!more) return;
        e = en;
    }
}

extern "C" void kernel_launch(void* const* d_in, const int* in_sizes, int n_in, void* d_out,
                              int out_size, void* d_ws, size_t ws_size, hipStream_t stream) {
    const float* x1 = (const float*)d_in[0];
    const float* x2 = (const float*)d_in[1];
    const float* w = (const float*)d_in[2];
    float* out = (float*)d_out;
    const int n = in_sizes[0] / DIM1_C;  // E
    int grid = 6 * 256;                  // 6 single-wave blocks per CU (LDS-limited)
    if (grid > n) grid = n;
    tp_kernel<<<grid, 64, 0, stream>>>(x1, x2, w, out, n);
}

// Round 5
// 246.040 us; speedup vs baseline: 1.0259x; 1.0259x over previous
//
#include <hip/hip_runtime.h>
#include <hip/hip_bf16.h>

// ---------------------------------------------------------------------------
// Compile-time computation of the real Wigner-3j tables, mirroring the Python
// reference (_cg, _w3j_complex, _Q, _real_w3j) in double precision.
// PATH_W = sqrt(2*lo+1) is folded into the tables.
// ---------------------------------------------------------------------------

struct Tbl { double v[5][5][5]; };   // max (2l+1)=5 per axis; zero padded
struct CMat { double re[5][5]; double im[5][5]; };

constexpr double cfact(int n) {
    double r = 1.0;
    for (int i = 2; i <= n; ++i) r *= (double)i;
    return r;
}

constexpr double csqrt(double x) {
    if (x <= 0.0) return 0.0;
    double g = x > 1.0 ? x : 1.0;
    for (int i = 0; i < 100; ++i) g = 0.5 * (g + x / g);
    return g;
}

constexpr int cparity(int k) { return (((k % 2) + 2) % 2 == 0) ? 1 : -1; }

constexpr double ccg(int l1, int l2, int l3, int m1, int m2, int m3) {
    if (m1 + m2 != m3) return 0.0;
    double pre = csqrt((2.0 * l3 + 1.0) * cfact(l3 + l1 - l2) * cfact(l3 - l1 + l2) *
                       cfact(l1 + l2 - l3) / cfact(l1 + l2 + l3 + 1));
    pre *= csqrt(cfact(l3 + m3) * cfact(l3 - m3) * cfact(l1 - m1) * cfact(l1 + m1) *
                 cfact(l2 - m2) * cfact(l2 + m2));
    int kmin = 0;
    if (l2 - l3 - m1 > kmin) kmin = l2 - l3 - m1;
    if (l1 - l3 + m2 > kmin) kmin = l1 - l3 + m2;
    int kmax = l1 + l2 - l3;
    if (l1 - m1 < kmax) kmax = l1 - m1;
    if (l2 + m2 < kmax) kmax = l2 + m2;
    double s = 0.0;
    for (int k = kmin; k <= kmax; ++k) {
        s += (double)cparity(k) /
             (cfact(k) * cfact(l1 + l2 - l3 - k) * cfact(l1 - m1 - k) * cfact(l2 + m2 - k) *
              cfact(l3 - l2 + m1 + k) * cfact(l3 - l1 - m2 + k));
    }
    return pre * s;
}

constexpr Tbl cw3j_complex(int l1, int l2, int l3) {
    Tbl w{};
    for (int m1 = -l1; m1 <= l1; ++m1)
        for (int m2 = -l2; m2 <= l2; ++m2) {
            int m3 = -(m1 + m2);
            if (m3 >= -l3 && m3 <= l3) {
                w.v[m1 + l1][m2 + l2][m3 + l3] =
                    (double)cparity(l1 - l2 - m3) * ccg(l1, l2, l3, m1, m2, m1 + m2) /
                    csqrt(2.0 * l3 + 1.0);
            }
        }
    return w;
}

constexpr CMat cQ(int l) {
    CMat q{};
    q.re[l][l] = 1.0;
    double s2 = csqrt(2.0);
    for (int m = 1; m <= l; ++m) {
        q.re[l + m][l + m] = (double)cparity(m) / s2;
        q.re[l + m][l - m] = 1.0 / s2;
        q.im[l - m][l - m] = 1.0 / s2;
        q.im[l - m][l + m] = -(double)cparity(m) / s2;
    }
    return q;
}

constexpr Tbl creal_w3j(int l1, int l2, int l3) {
    const CMat q1 = cQ(l1), q2 = cQ(l2), q3 = cQ(l3);
    const Tbl w = cw3j_complex(l1, l2, l3);
    const int n1 = 2 * l1 + 1, n2 = 2 * l2 + 1, n3 = 2 * l3 + 1;
    Tbl t1re{}, t1im{};
    for (int A = 0; A < n1; ++A)
        for (int B = 0; B < n2; ++B)
            for (int c = 0; c < n3; ++c) {
                double re = 0.0, im = 0.0;
                for (int C = 0; C < n3; ++C) {
                    re += w.v[A][B][C] * q3.re[c][C];
                    im += w.v[A][B][C] * q3.im[c][C];
                }
                t1re.v[A][B][c] = re;
                t1im.v[A][B][c] = im;
            }
    Tbl t2re{}, t2im{};
    for (int A = 0; A < n1; ++A)
        for (int b = 0; b < n2; ++b)
            for (int c = 0; c < n3; ++c) {
                double re = 0.0, im = 0.0;
                for (int B = 0; B < n2; ++B) {
                    re += q2.re[b][B] * t1re.v[A][B][c] - q2.im[b][B] * t1im.v[A][B][c];
                    im += q2.re[b][B] * t1im.v[A][B][c] + q2.im[b][B] * t1re.v[A][B][c];
                }
                t2re.v[A][b][c] = re;
                t2im.v[A][b][c] = im;
            }
    Tbl Tre{}, Tim{};
    for (int a = 0; a < n1; ++a)
        for (int b = 0; b < n2; ++b)
            for (int c = 0; c < n3; ++c) {
                double re = 0.0, im = 0.0;
                for (int A = 0; A < n1; ++A) {
                    re += q1.re[a][A] * t2re.v[A][b][c] - q1.im[a][A] * t2im.v[A][b][c];
                    im += q1.re[a][A] * t2im.v[A][b][c] + q1.im[a][A] * t2re.v[A][b][c];
                }
                Tre.v[a][b][c] = re;
                Tim.v[a][b][c] = im;
            }
    double nre = 0.0, nim = 0.0;
    for (int a = 0; a < n1; ++a)
        for (int b = 0; b < n2; ++b)
            for (int c = 0; c < n3; ++c) {
                nre += Tre.v[a][b][c] * Tre.v[a][b][c];
                nim += Tim.v[a][b][c] * Tim.v[a][b][c];
            }
    const bool useRe = (nre >= nim);
    const double norm = csqrt(useRe ? nre : nim);
    Tbl out{};
    for (int a = 0; a < n1; ++a)
        for (int b = 0; b < n2; ++b)
            for (int c = 0; c < n3; ++c) {
                float t32 = (float)((useRe ? Tre.v[a][b][c] : Tim.v[a][b][c]) / norm);
                out.v[a][b][c] = (double)t32 * csqrt(2.0 * l3 + 1.0);
            }
    return out;
}

constexpr Tbl CG[15] = {
    creal_w3j(0, 0, 0), creal_w3j(0, 1, 1), creal_w3j(0, 2, 2), creal_w3j(1, 0, 1),
    creal_w3j(1, 1, 0), creal_w3j(1, 1, 1), creal_w3j(1, 1, 2), creal_w3j(1, 2, 1),
    creal_w3j(1, 2, 2), creal_w3j(2, 0, 2), creal_w3j(2, 1, 1), creal_w3j(2, 1, 2),
    creal_w3j(2, 2, 0), creal_w3j(2, 2, 1), creal_w3j(2, 2, 2)};

// ---------------------------------------------------------------------------
// Kernel: 4 waves/block (256 thr), each wave fully independent with a PRIVATE
// 13 KB LDS slice and its own grid-stride element stream. No __syncthreads
// (no vmcnt drain). Per iteration:
//   prefetch frag(e+stride)  [issued BEFORE compute -> ~1000+ cy of cover]
//   compute frag(e) -> myLDS
//   lgkm fence               [ds_write -> ds_read ordering, cross-lane]
//   stream myLDS -> out[e] as float4
//   lgkm fence               [ds_read done before next iter's overwrite]
// 52 KB LDS/block -> 3 blocks/CU -> 12 waves/CU.
// ---------------------------------------------------------------------------

#define DIM1_C 576
#define DIM2_C 9
#define WDIM_C 960
#define ODIM_C 3264

__device__ __forceinline__ void lds_fence() {
    __builtin_amdgcn_sched_barrier(0);
    asm volatile("s_waitcnt lgkmcnt(0)" ::: "memory");
    __builtin_amdgcn_sched_barrier(0);
}

struct Frag {
    float a0[1], a1[3], a2[5];
    float b0[1], b1[3], b2[5];
    float w[15];
};

__device__ __forceinline__ void load_frag(const float* __restrict__ x1,
                                          const float* __restrict__ x2,
                                          const float* __restrict__ wgt, int e, int u, Frag& f) {
    const float* __restrict__ x1e = x1 + (size_t)e * DIM1_C;
    const float* __restrict__ x2e = x2 + (size_t)e * DIM2_C;
    const float* __restrict__ we = wgt + (size_t)e * WDIM_C;
    f.a0[0] = x1e[u];
#pragma unroll
    for (int i = 0; i < 3; ++i) f.a1[i] = x1e[64 + u * 3 + i];
#pragma unroll
    for (int i = 0; i < 5; ++i) f.a2[i] = x1e[256 + u * 5 + i];
    f.b0[0] = x2e[0];
#pragma unroll
    for (int j = 0; j < 3; ++j) f.b1[j] = x2e[1 + j];
#pragma unroll
    for (int j = 0; j < 5; ++j) f.b2[j] = x2e[4 + j];
#pragma unroll
    for (int p = 0; p < 15; ++p) f.w[p] = we[p * 64 + u];
}

template <int IDX, int N1, int N2, int N3>
__device__ __forceinline__ void do_path(const float (&a)[N1], const float (&b)[N2], float w,
                                        float* op) {
    float t[N3];
#pragma unroll
    for (int k = 0; k < N3; ++k) t[k] = 0.0f;
#pragma unroll
    for (int i = 0; i < N1; ++i) {
#pragma unroll
        for (int j = 0; j < N2; ++j) {
            const float p = a[i] * b[j];
#pragma unroll
            for (int k = 0; k < N3; ++k) {
                constexpr const Tbl& T = CG[IDX];
                const float c = (float)T.v[i][j][k];
                if (c != 0.0f) t[k] = fmaf(c, p, t[k]);
            }
        }
    }
#pragma unroll
    for (int k = 0; k < N3; ++k) op[k] = t[k] * w;
}

__device__ __forceinline__ void compute_to_lds(const Frag& f, float* buf, int u) {
    do_path<0, 1, 1, 1>(f.a0, f.b0, f.w[0], buf + 0 + u * 1);
    do_path<1, 1, 3, 3>(f.a0, f.b1, f.w[1], buf + 64 + u * 3);
    do_path<2, 1, 5, 5>(f.a0, f.b2, f.w[2], buf + 256 + u * 5);
    do_path<3, 3, 1, 3>(f.a1, f.b0, f.w[3], buf + 576 + u * 3);
    do_path<4, 3, 3, 1>(f.a1, f.b1, f.w[4], buf + 768 + u * 1);
    do_path<5, 3, 3, 3>(f.a1, f.b1, f.w[5], buf + 832 + u * 3);
    do_path<6, 3, 3, 5>(f.a1, f.b1, f.w[6], buf + 1024 + u * 5);
    do_path<7, 3, 5, 3>(f.a1, f.b2, f.w[7], buf + 1344 + u * 3);
    do_path<8, 3, 5, 5>(f.a1, f.b2, f.w[8], buf + 1536 + u * 5);
    do_path<9, 5, 1, 5>(f.a2, f.b0, f.w[9], buf + 1856 + u * 5);
    do_path<10, 5, 3, 3>(f.a2, f.b1, f.w[10], buf + 2176 + u * 3);
    do_path<11, 5, 3, 5>(f.a2, f.b1, f.w[11], buf + 2368 + u * 5);
    do_path<12, 5, 5, 1>(f.a2, f.b2, f.w[12], buf + 2688 + u * 1);
    do_path<13, 5, 5, 3>(f.a2, f.b2, f.w[13], buf + 2752 + u * 3);
    do_path<14, 5, 5, 5>(f.a2, f.b2, f.w[14], buf + 2944 + u * 5);
}

__device__ __forceinline__ void stream_out(const float* buf, float* __restrict__ out, int e,
                                           int u) {
    float4* __restrict__ outv = (float4*)(out + (size_t)e * ODIM_C);
    const float4* sv = (const float4*)buf;
#pragma unroll
    for (int it = 0; it < 12; ++it) outv[u + it * 64] = sv[u + it * 64];
    if (u < 48) outv[u + 768] = sv[u + 768];  // 816 = 12*64 + 48
}

__global__ __launch_bounds__(256) void tp_kernel(const float* __restrict__ x1,
                                                 const float* __restrict__ x2,
                                                 const float* __restrict__ wgt,
                                                 float* __restrict__ out, int n) {
    __shared__ __align__(16) float sbuf[4 * ODIM_C];  // 52,224 B; 13 KB per wave
    const int wv = threadIdx.x >> 6;
    const int u = threadIdx.x & 63;
    float* buf = &sbuf[wv * ODIM_C];

    const int nw = (int)gridDim.x * 4;          // total waves
    int e = (int)blockIdx.x * 4 + wv;           // this wave's first element
    if (e >= n) return;

    Frag f, g;
    load_frag(x1, x2, wgt, e, u, f);

    while (true) {
        // ---- stage A: consume f ----
        int en = e + nw;
        bool more = en < n;
        if (more) load_frag(x1, x2, wgt, en, u, g);  // prefetch BEFORE compute
        compute_to_lds(f, buf, u);
        lds_fence();                                 // ds_write -> ds_read
        stream_out(buf, out, e, u);
        if (!more) return;
        e = en;
        lds_fence();                                 // ds_read done before overwrite

        // ---- stage B: consume g ----
        en = e + nw;
        more = en < n;
        if (more) load_frag(x1, x2, wgt, en, u, f);  // prefetch BEFORE compute
        compute_to_lds(g, buf, u);
        lds_fence();
        stream_out(buf, out, e, u);
        if (!more) return;
        e = en;
        lds_fence();
    }
}

extern "C" void kernel_launch(void* const* d_in, const int* in_sizes, int n_in, void* d_out,
                              int out_size, void* d_ws, size_t ws_size, hipStream_t stream) {
    const float* x1 = (const float*)d_in[0];
    const float* x2 = (const float*)d_in[1];
    const float* w = (const float*)d_in[2];
    float* out = (float*)d_out;
    const int n = in_sizes[0] / DIM1_C;  // E
    int grid = 3 * 256;                  // 3 blocks/CU (LDS-limited), 12 waves/CU
    if (grid * 4 > n) grid = (n + 3) / 4;
    tp_kernel<<<grid, 256, 0, stream>>>(x1, x2, w, out, n);
}

// Round 7
// 222.214 us; speedup vs baseline: 1.1359x; 1.1072x over previous
//
#include <hip/hip_runtime.h>
#include <hip/hip_bf16.h>

// ---------------------------------------------------------------------------
// Compile-time computation of the real Wigner-3j tables, mirroring the Python
// reference (_cg, _w3j_complex, _Q, _real_w3j) in double precision.
// PATH_W = sqrt(2*lo+1) is folded into the tables.
// ---------------------------------------------------------------------------

struct Tbl { double v[5][5][5]; };   // max (2l+1)=5 per axis; zero padded
struct CMat { double re[5][5]; double im[5][5]; };

constexpr double cfact(int n) {
    double r = 1.0;
    for (int i = 2; i <= n; ++i) r *= (double)i;
    return r;
}

constexpr double csqrt(double x) {
    if (x <= 0.0) return 0.0;
    double g = x > 1.0 ? x : 1.0;
    for (int i = 0; i < 100; ++i) g = 0.5 * (g + x / g);
    return g;
}

constexpr int cparity(int k) { return (((k % 2) + 2) % 2 == 0) ? 1 : -1; }

constexpr double ccg(int l1, int l2, int l3, int m1, int m2, int m3) {
    if (m1 + m2 != m3) return 0.0;
    double pre = csqrt((2.0 * l3 + 1.0) * cfact(l3 + l1 - l2) * cfact(l3 - l1 + l2) *
                       cfact(l1 + l2 - l3) / cfact(l1 + l2 + l3 + 1));
    pre *= csqrt(cfact(l3 + m3) * cfact(l3 - m3) * cfact(l1 - m1) * cfact(l1 + m1) *
                 cfact(l2 - m2) * cfact(l2 + m2));
    int kmin = 0;
    if (l2 - l3 - m1 > kmin) kmin = l2 - l3 - m1;
    if (l1 - l3 + m2 > kmin) kmin = l1 - l3 + m2;
    int kmax = l1 + l2 - l3;
    if (l1 - m1 < kmax) kmax = l1 - m1;
    if (l2 + m2 < kmax) kmax = l2 + m2;
    double s = 0.0;
    for (int k = kmin; k <= kmax; ++k) {
        s += (double)cparity(k) /
             (cfact(k) * cfact(l1 + l2 - l3 - k) * cfact(l1 - m1 - k) * cfact(l2 + m2 - k) *
              cfact(l3 - l2 + m1 + k) * cfact(l3 - l1 - m2 + k));
    }
    return pre * s;
}

constexpr Tbl cw3j_complex(int l1, int l2, int l3) {
    Tbl w{};
    for (int m1 = -l1; m1 <= l1; ++m1)
        for (int m2 = -l2; m2 <= l2; ++m2) {
            int m3 = -(m1 + m2);
            if (m3 >= -l3 && m3 <= l3) {
                w.v[m1 + l1][m2 + l2][m3 + l3] =
                    (double)cparity(l1 - l2 - m3) * ccg(l1, l2, l3, m1, m2, m1 + m2) /
                    csqrt(2.0 * l3 + 1.0);
            }
        }
    return w;
}

constexpr CMat cQ(int l) {
    CMat q{};
    q.re[l][l] = 1.0;
    double s2 = csqrt(2.0);
    for (int m = 1; m <= l; ++m) {
        q.re[l + m][l + m] = (double)cparity(m) / s2;
        q.re[l + m][l - m] = 1.0 / s2;
        q.im[l - m][l - m] = 1.0 / s2;
        q.im[l - m][l + m] = -(double)cparity(m) / s2;
    }
    return q;
}

constexpr Tbl creal_w3j(int l1, int l2, int l3) {
    const CMat q1 = cQ(l1), q2 = cQ(l2), q3 = cQ(l3);
    const Tbl w = cw3j_complex(l1, l2, l3);
    const int n1 = 2 * l1 + 1, n2 = 2 * l2 + 1, n3 = 2 * l3 + 1;
    Tbl t1re{}, t1im{};
    for (int A = 0; A < n1; ++A)
        for (int B = 0; B < n2; ++B)
            for (int c = 0; c < n3; ++c) {
                double re = 0.0, im = 0.0;
                for (int C = 0; C < n3; ++C) {
                    re += w.v[A][B][C] * q3.re[c][C];
                    im += w.v[A][B][C] * q3.im[c][C];
                }
                t1re.v[A][B][c] = re;
                t1im.v[A][B][c] = im;
            }
    Tbl t2re{}, t2im{};
    for (int A = 0; A < n1; ++A)
        for (int b = 0; b < n2; ++b)
            for (int c = 0; c < n3; ++c) {
                double re = 0.0, im = 0.0;
                for (int B = 0; B < n2; ++B) {
                    re += q2.re[b][B] * t1re.v[A][B][c] - q2.im[b][B] * t1im.v[A][B][c];
                    im += q2.re[b][B] * t1im.v[A][B][c] + q2.im[b][B] * t1re.v[A][B][c];
                }
                t2re.v[A][b][c] = re;
                t2im.v[A][b][c] = im;
            }
    Tbl Tre{}, Tim{};
    for (int a = 0; a < n1; ++a)
        for (int b = 0; b < n2; ++b)
            for (int c = 0; c < n3; ++c) {
                double re = 0.0, im = 0.0;
                for (int A = 0; A < n1; ++A) {
                    re += q1.re[a][A] * t2re.v[A][b][c] - q1.im[a][A] * t2im.v[A][b][c];
                    im += q1.re[a][A] * t2im.v[A][b][c] + q1.im[a][A] * t2re.v[A][b][c];
                }
                Tre.v[a][b][c] = re;
                Tim.v[a][b][c] = im;
            }
    double nre = 0.0, nim = 0.0;
    for (int a = 0; a < n1; ++a)
        for (int b = 0; b < n2; ++b)
            for (int c = 0; c < n3; ++c) {
                nre += Tre.v[a][b][c] * Tre.v[a][b][c];
                nim += Tim.v[a][b][c] * Tim.v[a][b][c];
            }
    const bool useRe = (nre >= nim);
    const double norm = csqrt(useRe ? nre : nim);
    Tbl out{};
    for (int a = 0; a < n1; ++a)
        for (int b = 0; b < n2; ++b)
            for (int c = 0; c < n3; ++c) {
                float t32 = (float)((useRe ? Tre.v[a][b][c] : Tim.v[a][b][c]) / norm);
                out.v[a][b][c] = (double)t32 * csqrt(2.0 * l3 + 1.0);
            }
    return out;
}

constexpr Tbl CG[15] = {
    creal_w3j(0, 0, 0), creal_w3j(0, 1, 1), creal_w3j(0, 2, 2), creal_w3j(1, 0, 1),
    creal_w3j(1, 1, 0), creal_w3j(1, 1, 1), creal_w3j(1, 1, 2), creal_w3j(1, 2, 1),
    creal_w3j(1, 2, 2), creal_w3j(2, 0, 2), creal_w3j(2, 1, 1), creal_w3j(2, 1, 2),
    creal_w3j(2, 2, 0), creal_w3j(2, 2, 1), creal_w3j(2, 2, 2)};

// ---------------------------------------------------------------------------
// Kernel: R1 structure (4 waves/block, one element per wave, LDS staging,
// __syncthreads, block-cooperative float4 stream-out) with ONE change:
// NONTEMPORAL loads (x1, weight) and stores (out). All traffic here is
// strictly streaming (zero reuse) — nt bypasses cache allocation churn.
// Native clang vector type used for the NT builtins (HIP float4 rejected).
// ---------------------------------------------------------------------------

#define DIM1_C 576
#define DIM2_C 9
#define WDIM_C 960
#define ODIM_C 3264
#define EPB 4  // elements (waves) per block

typedef float f32x4 __attribute__((ext_vector_type(4)));

template <int IDX, int N1, int N2, int N3>
__device__ __forceinline__ void do_path(const float (&a)[N1], const float (&b)[N2], float w,
                                        float* op) {
    float t[N3];
#pragma unroll
    for (int k = 0; k < N3; ++k) t[k] = 0.0f;
#pragma unroll
    for (int i = 0; i < N1; ++i) {
#pragma unroll
        for (int j = 0; j < N2; ++j) {
            const float p = a[i] * b[j];
#pragma unroll
            for (int k = 0; k < N3; ++k) {
                constexpr const Tbl& T = CG[IDX];
                const float c = (float)T.v[i][j][k];
                if (c != 0.0f) t[k] = fmaf(c, p, t[k]);
            }
        }
    }
#pragma unroll
    for (int k = 0; k < N3; ++k) op[k] = t[k] * w;
}

__global__ __launch_bounds__(256) void tp_kernel(const float* __restrict__ x1,
                                                 const float* __restrict__ x2,
                                                 const float* __restrict__ wgt,
                                                 float* __restrict__ out, int n) {
    __shared__ __align__(16) float sout[EPB * ODIM_C];  // 52,224 B

    const int wv = threadIdx.x >> 6;  // wave in block
    const int u = threadIdx.x & 63;   // lane = mul channel
    const int e = blockIdx.x * EPB + wv;

    if (e < n) {
        const float* __restrict__ x1e = x1 + (size_t)e * DIM1_C;
        const float* __restrict__ x2e = x2 + (size_t)e * DIM2_C;
        const float* __restrict__ we = wgt + (size_t)e * WDIM_C;
        float* oe = &sout[wv * ODIM_C];

        // x1 slices for this channel (nontemporal: streaming, no reuse)
        float a0[1], a1[3], a2[5];
        a0[0] = __builtin_nontemporal_load(&x1e[u]);
#pragma unroll
        for (int i = 0; i < 3; ++i) a1[i] = __builtin_nontemporal_load(&x1e[64 + u * 3 + i]);
#pragma unroll
        for (int i = 0; i < 5; ++i) a2[i] = __builtin_nontemporal_load(&x1e[256 + u * 5 + i]);

        // x2 slices (uniform across the wave; tiny — keep cached path)
        float b0[1], b1[3], b2[5];
        b0[0] = x2e[0];
#pragma unroll
        for (int j = 0; j < 3; ++j) b1[j] = x2e[1 + j];
#pragma unroll
        for (int j = 0; j < 5; ++j) b2[j] = x2e[4 + j];

        // weights (nontemporal)
        float w[15];
#pragma unroll
        for (int p = 0; p < 15; ++p) w[p] = __builtin_nontemporal_load(&we[p * 64 + u]);

        do_path<0, 1, 1, 1>(a0, b0, w[0], oe + 0 + u * 1);
        do_path<1, 1, 3, 3>(a0, b1, w[1], oe + 64 + u * 3);
        do_path<2, 1, 5, 5>(a0, b2, w[2], oe + 256 + u * 5);
        do_path<3, 3, 1, 3>(a1, b0, w[3], oe + 576 + u * 3);
        do_path<4, 3, 3, 1>(a1, b1, w[4], oe + 768 + u * 1);
        do_path<5, 3, 3, 3>(a1, b1, w[5], oe + 832 + u * 3);
        do_path<6, 3, 3, 5>(a1, b1, w[6], oe + 1024 + u * 5);
        do_path<7, 3, 5, 3>(a1, b2, w[7], oe + 1344 + u * 3);
        do_path<8, 3, 5, 5>(a1, b2, w[8], oe + 1536 + u * 5);
        do_path<9, 5, 1, 5>(a2, b0, w[9], oe + 1856 + u * 5);
        do_path<10, 5, 3, 3>(a2, b1, w[10], oe + 2176 + u * 3);
        do_path<11, 5, 3, 5>(a2, b1, w[11], oe + 2368 + u * 5);
        do_path<12, 5, 5, 1>(a2, b2, w[12], oe + 2688 + u * 1);
        do_path<13, 5, 5, 3>(a2, b2, w[13], oe + 2752 + u * 3);
        do_path<14, 5, 5, 5>(a2, b2, w[14], oe + 2944 + u * 5);
    }

    __syncthreads();

    // Cooperative nontemporal float4 streaming store of the block's output tile.
    const int base_e = blockIdx.x * EPB;
    int nvalid = n - base_e;
    if (nvalid > EPB) nvalid = EPB;
    if (nvalid <= 0) return;
    const int total4 = nvalid * (ODIM_C / 4);  // float4 count
    f32x4* __restrict__ outv = (f32x4*)(out + (size_t)base_e * ODIM_C);
    const f32x4* sv = (const f32x4*)&sout[0];
    for (int i = threadIdx.x; i < total4; i += 256) {
        f32x4 v = sv[i];
        __builtin_nontemporal_store(v, &outv[i]);
    }
}

extern "C" void kernel_launch(void* const* d_in, const int* in_sizes, int n_in, void* d_out,
                              int out_size, void* d_ws, size_t ws_size, hipStream_t stream) {
    const float* x1 = (const float*)d_in[0];
    const float* x2 = (const float*)d_in[1];
    const float* w = (const float*)d_in[2];
    float* out = (float*)d_out;
    const int n = in_sizes[0] / DIM1_C;  // E
    const int grid = (n + EPB - 1) / EPB;
    tp_kernel<<<grid, 256, 0, stream>>>(x1, x2, w, out, n);
}

// Round 8
// 211.440 us; speedup vs baseline: 1.1938x; 1.0510x over previous
//
#include <hip/hip_runtime.h>
#include <hip/hip_bf16.h>

// ---------------------------------------------------------------------------
// Compile-time computation of the real Wigner-3j tables, mirroring the Python
// reference (_cg, _w3j_complex, _Q, _real_w3j) in double precision.
// PATH_W = sqrt(2*lo+1) is folded into the tables.
// ---------------------------------------------------------------------------

struct Tbl { double v[5][5][5]; };   // max (2l+1)=5 per axis; zero padded
struct CMat { double re[5][5]; double im[5][5]; };

constexpr double cfact(int n) {
    double r = 1.0;
    for (int i = 2; i <= n; ++i) r *= (double)i;
    return r;
}

constexpr double csqrt(double x) {
    if (x <= 0.0) return 0.0;
    double g = x > 1.0 ? x : 1.0;
    for (int i = 0; i < 100; ++i) g = 0.5 * (g + x / g);
    return g;
}

constexpr int cparity(int k) { return (((k % 2) + 2) % 2 == 0) ? 1 : -1; }

constexpr double ccg(int l1, int l2, int l3, int m1, int m2, int m3) {
    if (m1 + m2 != m3) return 0.0;
    double pre = csqrt((2.0 * l3 + 1.0) * cfact(l3 + l1 - l2) * cfact(l3 - l1 + l2) *
                       cfact(l1 + l2 - l3) / cfact(l1 + l2 + l3 + 1));
    pre *= csqrt(cfact(l3 + m3) * cfact(l3 - m3) * cfact(l1 - m1) * cfact(l1 + m1) *
                 cfact(l2 - m2) * cfact(l2 + m2));
    int kmin = 0;
    if (l2 - l3 - m1 > kmin) kmin = l2 - l3 - m1;
    if (l1 - l3 + m2 > kmin) kmin = l1 - l3 + m2;
    int kmax = l1 + l2 - l3;
    if (l1 - m1 < kmax) kmax = l1 - m1;
    if (l2 + m2 < kmax) kmax = l2 + m2;
    double s = 0.0;
    for (int k = kmin; k <= kmax; ++k) {
        s += (double)cparity(k) /
             (cfact(k) * cfact(l1 + l2 - l3 - k) * cfact(l1 - m1 - k) * cfact(l2 + m2 - k) *
              cfact(l3 - l2 + m1 + k) * cfact(l3 - l1 - m2 + k));
    }
    return pre * s;
}

constexpr Tbl cw3j_complex(int l1, int l2, int l3) {
    Tbl w{};
    for (int m1 = -l1; m1 <= l1; ++m1)
        for (int m2 = -l2; m2 <= l2; ++m2) {
            int m3 = -(m1 + m2);
            if (m3 >= -l3 && m3 <= l3) {
                w.v[m1 + l1][m2 + l2][m3 + l3] =
                    (double)cparity(l1 - l2 - m3) * ccg(l1, l2, l3, m1, m2, m1 + m2) /
                    csqrt(2.0 * l3 + 1.0);
            }
        }
    return w;
}

constexpr CMat cQ(int l) {
    CMat q{};
    q.re[l][l] = 1.0;
    double s2 = csqrt(2.0);
    for (int m = 1; m <= l; ++m) {
        q.re[l + m][l + m] = (double)cparity(m) / s2;
        q.re[l + m][l - m] = 1.0 / s2;
        q.im[l - m][l - m] = 1.0 / s2;
        q.im[l - m][l + m] = -(double)cparity(m) / s2;
    }
    return q;
}

constexpr Tbl creal_w3j(int l1, int l2, int l3) {
    const CMat q1 = cQ(l1), q2 = cQ(l2), q3 = cQ(l3);
    const Tbl w = cw3j_complex(l1, l2, l3);
    const int n1 = 2 * l1 + 1, n2 = 2 * l2 + 1, n3 = 2 * l3 + 1;
    Tbl t1re{}, t1im{};
    for (int A = 0; A < n1; ++A)
        for (int B = 0; B < n2; ++B)
            for (int c = 0; c < n3; ++c) {
                double re = 0.0, im = 0.0;
                for (int C = 0; C < n3; ++C) {
                    re += w.v[A][B][C] * q3.re[c][C];
                    im += w.v[A][B][C] * q3.im[c][C];
                }
                t1re.v[A][B][c] = re;
                t1im.v[A][B][c] = im;
            }
    Tbl t2re{}, t2im{};
    for (int A = 0; A < n1; ++A)
        for (int b = 0; b < n2; ++b)
            for (int c = 0; c < n3; ++c) {
                double re = 0.0, im = 0.0;
                for (int B = 0; B < n2; ++B) {
                    re += q2.re[b][B] * t1re.v[A][B][c] - q2.im[b][B] * t1im.v[A][B][c];
                    im += q2.re[b][B] * t1im.v[A][B][c] + q2.im[b][B] * t1re.v[A][B][c];
                }
                t2re.v[A][b][c] = re;
                t2im.v[A][b][c] = im;
            }
    Tbl Tre{}, Tim{};
    for (int a = 0; a < n1; ++a)
        for (int b = 0; b < n2; ++b)
            for (int c = 0; c < n3; ++c) {
                double re = 0.0, im = 0.0;
                for (int A = 0; A < n1; ++A) {
                    re += q1.re[a][A] * t2re.v[A][b][c] - q1.im[a][A] * t2im.v[A][b][c];
                    im += q1.re[a][A] * t2im.v[A][b][c] + q1.im[a][A] * t2re.v[A][b][c];
                }
                Tre.v[a][b][c] = re;
                Tim.v[a][b][c] = im;
            }
    double nre = 0.0, nim = 0.0;
    for (int a = 0; a < n1; ++a)
        for (int b = 0; b < n2; ++b)
            for (int c = 0; c < n3; ++c) {
                nre += Tre.v[a][b][c] * Tre.v[a][b][c];
                nim += Tim.v[a][b][c] * Tim.v[a][b][c];
            }
    const bool useRe = (nre >= nim);
    const double norm = csqrt(useRe ? nre : nim);
    Tbl out{};
    for (int a = 0; a < n1; ++a)
        for (int b = 0; b < n2; ++b)
            for (int c = 0; c < n3; ++c) {
                float t32 = (float)((useRe ? Tre.v[a][b][c] : Tim.v[a][b][c]) / norm);
                out.v[a][b][c] = (double)t32 * csqrt(2.0 * l3 + 1.0);
            }
    return out;
}

constexpr Tbl CG[15] = {
    creal_w3j(0, 0, 0), creal_w3j(0, 1, 1), creal_w3j(0, 2, 2), creal_w3j(1, 0, 1),
    creal_w3j(1, 1, 0), creal_w3j(1, 1, 1), creal_w3j(1, 1, 2), creal_w3j(1, 2, 1),
    creal_w3j(1, 2, 2), creal_w3j(2, 0, 2), creal_w3j(2, 1, 1), creal_w3j(2, 1, 2),
    creal_w3j(2, 2, 0), creal_w3j(2, 2, 1), creal_w3j(2, 2, 2)};

// ---------------------------------------------------------------------------
// Kernel: R6 structure (4 waves/block, one element/wave, private LDS slice,
// __syncthreads + block-cooperative NT float4 stream-out) with ONE change:
// x1 is staged into the wave's LDS slice via fully-coalesced f32x4 NT loads,
// then the per-lane stride-3/stride-5 a-slices are read from LDS (bank-free:
// strides coprime with 32). Removes the only non-coalesced global reads.
// ---------------------------------------------------------------------------

#define DIM1_C 576
#define DIM2_C 9
#define WDIM_C 960
#define ODIM_C 3264
#define EPB 4  // elements (waves) per block

typedef float f32x4 __attribute__((ext_vector_type(4)));

__device__ __forceinline__ void lds_fence() {
    __builtin_amdgcn_sched_barrier(0);
    asm volatile("s_waitcnt lgkmcnt(0)" ::: "memory");
    __builtin_amdgcn_sched_barrier(0);
}

template <int IDX, int N1, int N2, int N3>
__device__ __forceinline__ void do_path(const float (&a)[N1], const float (&b)[N2], float w,
                                        float* op) {
    float t[N3];
#pragma unroll
    for (int k = 0; k < N3; ++k) t[k] = 0.0f;
#pragma unroll
    for (int i = 0; i < N1; ++i) {
#pragma unroll
        for (int j = 0; j < N2; ++j) {
            const float p = a[i] * b[j];
#pragma unroll
            for (int k = 0; k < N3; ++k) {
                constexpr const Tbl& T = CG[IDX];
                const float c = (float)T.v[i][j][k];
                if (c != 0.0f) t[k] = fmaf(c, p, t[k]);
            }
        }
    }
#pragma unroll
    for (int k = 0; k < N3; ++k) op[k] = t[k] * w;
}

__global__ __launch_bounds__(256) void tp_kernel(const float* __restrict__ x1,
                                                 const float* __restrict__ x2,
                                                 const float* __restrict__ wgt,
                                                 float* __restrict__ out, int n) {
    __shared__ __align__(16) float sout[EPB * ODIM_C];  // 52,224 B

    const int wv = threadIdx.x >> 6;  // wave in block
    const int u = threadIdx.x & 63;   // lane = mul channel
    const int e = blockIdx.x * EPB + wv;

    if (e < n) {
        const float* __restrict__ x1e = x1 + (size_t)e * DIM1_C;
        const float* __restrict__ x2e = x2 + (size_t)e * DIM2_C;
        const float* __restrict__ we = wgt + (size_t)e * WDIM_C;
        float* oe = &sout[wv * ODIM_C];

        // ---- stage x1[e] (576 floats) into the wave's LDS slice, coalesced ----
        {
            const f32x4* __restrict__ x1v = (const f32x4*)x1e;  // 144 vec4s
            f32x4* ov = (f32x4*)oe;
            f32x4 v0 = __builtin_nontemporal_load(&x1v[u]);
            f32x4 v1 = __builtin_nontemporal_load(&x1v[64 + u]);
            ov[u] = v0;
            ov[64 + u] = v1;
            if (u < 16) {
                f32x4 v2 = __builtin_nontemporal_load(&x1v[128 + u]);
                ov[128 + u] = v2;
            }
        }
        lds_fence();  // cross-lane handoff: staged writes -> strided reads

        // per-lane a-slices from LDS (strides 3/5 dwords: coprime w/ 32 banks)
        float a0[1], a1[3], a2[5];
        a0[0] = oe[u];
#pragma unroll
        for (int i = 0; i < 3; ++i) a1[i] = oe[64 + u * 3 + i];
#pragma unroll
        for (int i = 0; i < 5; ++i) a2[i] = oe[256 + u * 5 + i];

        // x2 slices (uniform across the wave; tiny — cached path)
        float b0[1], b1[3], b2[5];
        b0[0] = x2e[0];
#pragma unroll
        for (int j = 0; j < 3; ++j) b1[j] = x2e[1 + j];
#pragma unroll
        for (int j = 0; j < 5; ++j) b2[j] = x2e[4 + j];

        // weights (nontemporal, coalesced)
        float w[15];
#pragma unroll
        for (int p = 0; p < 15; ++p) w[p] = __builtin_nontemporal_load(&we[p * 64 + u]);

        // all 9 a-values are in registers; outputs may now overwrite the slice
        do_path<0, 1, 1, 1>(a0, b0, w[0], oe + 0 + u * 1);
        do_path<1, 1, 3, 3>(a0, b1, w[1], oe + 64 + u * 3);
        do_path<2, 1, 5, 5>(a0, b2, w[2], oe + 256 + u * 5);
        do_path<3, 3, 1, 3>(a1, b0, w[3], oe + 576 + u * 3);
        do_path<4, 3, 3, 1>(a1, b1, w[4], oe + 768 + u * 1);
        do_path<5, 3, 3, 3>(a1, b1, w[5], oe + 832 + u * 3);
        do_path<6, 3, 3, 5>(a1, b1, w[6], oe + 1024 + u * 5);
        do_path<7, 3, 5, 3>(a1, b2, w[7], oe + 1344 + u * 3);
        do_path<8, 3, 5, 5>(a1, b2, w[8], oe + 1536 + u * 5);
        do_path<9, 5, 1, 5>(a2, b0, w[9], oe + 1856 + u * 5);
        do_path<10, 5, 3, 3>(a2, b1, w[10], oe + 2176 + u * 3);
        do_path<11, 5, 3, 5>(a2, b1, w[11], oe + 2368 + u * 5);
        do_path<12, 5, 5, 1>(a2, b2, w[12], oe + 2688 + u * 1);
        do_path<13, 5, 5, 3>(a2, b2, w[13], oe + 2752 + u * 3);
        do_path<14, 5, 5, 5>(a2, b2, w[14], oe + 2944 + u * 5);
    }

    __syncthreads();

    // Cooperative nontemporal float4 streaming store of the block's output tile.
    const int base_e = blockIdx.x * EPB;
    int nvalid = n - base_e;
    if (nvalid > EPB) nvalid = EPB;
    if (nvalid <= 0) return;
    const int total4 = nvalid * (ODIM_C / 4);  // float4 count
    f32x4* __restrict__ outv = (f32x4*)(out + (size_t)base_e * ODIM_C);
    const f32x4* sv = (const f32x4*)&sout[0];
    for (int i = threadIdx.x; i < total4; i += 256) {
        f32x4 v = sv[i];
        __builtin_nontemporal_store(v, &outv[i]);
    }
}

extern "C" void kernel_launch(void* const* d_in, const int* in_sizes, int n_in, void* d_out,
                              int out_size, void* d_ws, size_t ws_size, hipStream_t stream) {
    const float* x1 = (const float*)d_in[0];
    const float* x2 = (const float*)d_in[1];
    const float* w = (const float*)d_in[2];
    float* out = (float*)d_out;
    const int n = in_sizes[0] / DIM1_C;  // E
    const int grid = (n + EPB - 1) / EPB;
    tp_kernel<<<grid, 256, 0, stream>>>(x1, x2, w, out, n);
}